// Round 2
// baseline (787.143 us; speedup 1.0000x reference)
//
#include <hip/hip_runtime.h>

typedef unsigned char u8;

#define TT 1024
#define BB 512
#define LL 50
#define STOPI 48
#define STARTI 49
#define NEGV -10000.0f

// ws layout (new path):
//   [0, 2048)                  : int idx[512]
//   [4096, 4096+B*50*T)        : u8 ptr[B][50][T]   backpointers, [label][time]
//   [4096+B*50*T, +B*T*50*4)   : f32 vit[B][T][50]  per-step Viterbi rows
#define PTR_OFF   4096
#define PTR_BYTES ((size_t)BB * TT * LL)
#define VIT_OFF   (PTR_OFF + PTR_BYTES)
#define VIT_BYTES ((size_t)BB * TT * LL * 4)
#define NEED_WS   (VIT_OFF + VIT_BYTES)

// value-max over a[0..49] via max3 tree (vcc-free, ~26 instrs)
#define MAX50(A, M)                                                            \
    {                                                                          \
        float r0_[17];                                                         \
        _Pragma("unroll")                                                      \
        for (int k_ = 0; k_ < 16; ++k_)                                        \
            r0_[k_] = fmaxf(fmaxf((A)[3*k_], (A)[3*k_+1]), (A)[3*k_+2]);       \
        r0_[16] = fmaxf((A)[48], (A)[49]);                                     \
        float r1_[6];                                                          \
        _Pragma("unroll")                                                      \
        for (int k_ = 0; k_ < 5; ++k_)                                         \
            r1_[k_] = fmaxf(fmaxf(r0_[3*k_], r0_[3*k_+1]), r0_[3*k_+2]);       \
        r1_[5] = fmaxf(r0_[15], r0_[16]);                                      \
        (M) = fmaxf(fmaxf(fmaxf(r1_[0], r1_[1]), r1_[2]),                      \
                    fmaxf(fmaxf(r1_[3], r1_[4]), r1_[5]));                     \
    }

// ---------------------------------------------------------------------------
// K1: serial max-only Viterbi chain. One wave per batch; lane = 'to' label.
// Per step: 50 readlane-broadcasts + 50 adds + max3 tree. NO argmax, NO cmp
// chains, NO barriers, NO LDS. vit_t rows streamed to global for K2.
// ---------------------------------------------------------------------------
__global__ __launch_bounds__(64) void viterbi_max(
    const float* __restrict__ feats, const int* __restrict__ lens,
    const float* __restrict__ trans, float* __restrict__ out_scores,
    int* __restrict__ idx_ws, float* __restrict__ vit_ws)
{
    const int b    = blockIdx.x;
    const int lane = threadIdx.x;
    if (lane >= LL) return;                       // no barriers below; safe

    float trr[LL];
#pragma unroll
    for (int j = 0; j < LL; ++j) trr[j] = trans[lane * LL + j];
    const float tr_stop = trans[STOPI * LL + lane];
    const int len = lens[b];

    float vit = (lane == STARTI) ? 0.0f : NEGV;

    const float* fb  = feats  + (size_t)b * (TT * LL);
    float*       vst = vit_ws + (size_t)b * (TT * LL);

    // feats register ring, prefetch depth 4 (covers HBM latency)
    float f0 = fb[0 * LL + lane];
    float f1 = fb[1 * LL + lane];
    float f2 = fb[2 * LL + lane];
    float f3 = fb[3 * LL + lane];

#define K1STEP(T, F)                                                           \
    {                                                                          \
        if ((T) < len) {                                                       \
            vst[(size_t)(T) * LL + lane] = vit;   /* row t = pre-update vit */ \
            const float fc_ = (F);                                             \
            { int tp_ = (T) + 4; if (tp_ > TT - 1) tp_ = TT - 1;               \
              (F) = fb[(size_t)tp_ * LL + lane]; }                             \
            float a_[LL];                                                      \
            _Pragma("unroll")                                                  \
            for (int j_ = 0; j_ < LL; ++j_)                                    \
                a_[j_] = __int_as_float(__builtin_amdgcn_readlane(             \
                             __float_as_int(vit), j_)) + trr[j_];              \
            float m_; MAX50(a_, m_)                                            \
            float nv_ = m_ + fc_;                                              \
            if ((T) == len - 1) nv_ += tr_stop;                                \
            vit = nv_;                                                         \
        }                                                                      \
    }

    const int nq = (len + 3) >> 2;
    for (int q = 0; q < nq; ++q) {
        const int tb = q << 2;
        K1STEP(tb + 0, f0)
        K1STEP(tb + 1, f1)
        K1STEP(tb + 2, f2)
        K1STEP(tb + 3, f3)
    }
#undef K1STEP

    // row 'len' (frozen vit) for K2's min(t, len) lookup
    if (len < TT) vst[(size_t)len * LL + lane] = vit;

    // final score / first-index argmax (one-time)
    float m = -3.4e38f; int mi = 0;
#pragma unroll
    for (int j = 0; j < LL; ++j) {
        float s = __int_as_float(__builtin_amdgcn_readlane(__float_as_int(vit), j));
        if (s > m) { m = s; mi = j; }
    }
    if (lane == 0) { out_scores[b] = m; idx_ws[b] = mi; }
}

// ---------------------------------------------------------------------------
// K2: backpointer recompute, massively parallel. One wave per (b, 8-step
// group); lane = 'to'. For each needed row r = min(t,len): s_j = vit[r][j] +
// trr[j] (bitwise identical to K1's values), m via max tree (exact selection,
// association-free), idx = first j with s_j == m  == reference argmax.
// Frozen rows (t >= len) dedupe to one compute per group.
// ---------------------------------------------------------------------------
__global__ __launch_bounds__(256) void viterbi_ptr(
    const int* __restrict__ lens, const float* __restrict__ trans,
    const float* __restrict__ vit_ws, u8* __restrict__ ptr_ws)
{
    const int tid  = threadIdx.x;
    const int lane = tid & 63;
    if (lane >= LL) return;                        // no barriers below
    const int wid = (blockIdx.x << 2) | (tid >> 6);
    const int b   = wid >> 7;                      // 128 waves per batch
    const int t0  = (wid & 127) << 3;              // this wave's 8 steps

    float trr[LL];
#pragma unroll
    for (int j = 0; j < LL; ++j) trr[j] = trans[lane * LL + j];
    const int len = lens[b];

    const float* vbase = vit_ws + (size_t)b * (TT * LL);
    u8* pt = ptr_ws + (size_t)b * (TT * LL) + (size_t)lane * TT;  // [to][t]

    unsigned pk0 = 0, pk1 = 0;
    int prev_r = -1, idx = 0;
#pragma unroll
    for (int g = 0; g < 8; ++g) {
        const int t = t0 + g;
        const int r = (t < len) ? t : len;         // frozen rows collapse
        if (r != prev_r) {
            prev_r = r;
            const float v = vbase[(size_t)r * LL + lane];
            float a[LL];
#pragma unroll
            for (int j = 0; j < LL; ++j)
                a[j] = __int_as_float(__builtin_amdgcn_readlane(
                           __float_as_int(v), j)) + trr[j];
            float m; MAX50(a, m)
            int ii = 0;
#pragma unroll
            for (int j = LL - 1; j >= 0; --j)      // descending: first index wins
                if (a[j] == m) ii = j;
            idx = ii;
        }
        if (g < 4) pk0 |= ((unsigned)idx) << (8 * g);
        else       pk1 |= ((unsigned)idx) << (8 * (g - 4));
    }
    *(unsigned*)(pt + t0)     = pk0;
    *(unsigned*)(pt + t0 + 4) = pk1;
}

// ---------------------------------------------------------------------------
// K3: backtrack with chunked pointer-jumping. XOR-swizzled LDS layout:
// byte (s,t) lives at (s<<10) + (t ^ ((s&31)<<2))  -> phase-1's same-t reads
// spread across all 32 banks (was 64-way conflict: st*1024/4 % 32 == 0).
// ---------------------------------------------------------------------------
#define LSW(S, T) (((S) << 10) + ((T) ^ (((S) & 31) << 2)))

__global__ __launch_bounds__(64) void viterbi_bwd(
    const int* __restrict__ idx_ws, const u8* __restrict__ ptr_ws,
    float* __restrict__ out_paths)
{
    const int b = blockIdx.x;
    const int lane = threadIdx.x;

    __shared__ u8 lptr[TT * LL];    // 51200 B, swizzled [label][t]
    __shared__ u8 maps[32 * LL];
    __shared__ int entries[33];

    {   // dword-level swizzled copy (XOR touches bits 0..4 of the dword index)
        const unsigned* src = (const unsigned*)(ptr_ws + (size_t)b * TT * LL);
        unsigned* dst = (unsigned*)lptr;
        for (int i = lane; i < (TT * LL) / 4; i += 64) {
            const int to = i >> 8;            // 256 dwords per label row
            const int t4 = i & 255;
            dst[(to << 8) + (t4 ^ (to & 31))] = src[i];
        }
    }
    __syncthreads();

    // phase 1: all 1600 (chunk, entry) walks; 25 chains per lane
    {
        int st[25], tt[25], cidx[25];
#pragma unroll
        for (int k = 0; k < 25; ++k) {
            int w = k * 64 + lane;
            int c = w / 50;
            int l = w - c * 50;
            st[k] = l;
            tt[k] = c * 32 + 31;
            cidx[k] = c * 50 + l;
        }
        for (int j = 0; j < 32; ++j) {
#pragma unroll
            for (int k = 0; k < 25; ++k) {
                st[k] = lptr[LSW(st[k], tt[k])];
                tt[k] -= 1;
            }
        }
#pragma unroll
        for (int k = 0; k < 25; ++k) maps[cidx[k]] = (u8)st[k];
    }
    __syncthreads();

    const int idx = idx_ws[b];

    // phase 2: compose chunk maps sequentially
    if (lane == 0) {
        int i = idx;
        for (int c = 31; c >= 0; --c) {
            entries[c + 1] = i;
            i = maps[c * 50 + i];
        }
        entries[0] = i;
    }
    __syncthreads();

    // phase 3: re-walk all 32 chunks in parallel, writing the path
    float* po = out_paths + (size_t)b * TT;
    if (lane < 32) {
        const int c = lane;
        int s = entries[c + 1];
        for (int j = 0; j < 32; ++j) {
            int t = c * 32 + 31 - j;
            int ni = lptr[LSW(s, t)];
            if (t > 0) po[t - 1] = (float)ni;
            s = ni;
        }
    }
    if (lane == 0) po[TT - 1] = (float)idx;
}

// ---------------------------------------------------------------------------
// Fallback fwd (known-good 4-wave cooperative kernel) if workspace is small.
// ---------------------------------------------------------------------------
__global__ __launch_bounds__(256) void viterbi_fwd_fb(
    const float* __restrict__ feats, const int* __restrict__ lens,
    const float* __restrict__ trans, float* __restrict__ out_scores,
    int* __restrict__ idx_ws, u8* __restrict__ ptr_ws)
{
    const int b    = blockIdx.x;
    const int tid  = threadIdx.x;
    const int lane = tid & 63;
    const int w    = __builtin_amdgcn_readfirstlane(tid >> 6);
    const int off  = w * 13;
    const int row  = (lane < LL) ? lane : (LL - 1);

    float trrv[13];
#pragma unroll
    for (int jj = 0; jj < 13; ++jj) {
        const int j = off + jj;
        trrv[jj] = (j < LL) ? trans[row * LL + j] : -1.0e5f;
    }
    const float tr_stop = trans[STOPI * LL + row];
    const int len = lens[b];
    const int nchunks = (len + 15) >> 4;

    float vit = (lane == STARTI) ? 0.0f : NEGV;

    __shared__ float  featbuf[1024];
    __shared__ float2 partial[2][4][64];

    const float* fb = feats + (size_t)b * (TT * LL);
    u8* pt = ptr_ws + (size_t)b * (TT * LL) + (size_t)row * TT;

    const int ld = (tid < 200) ? tid : 199;
    float4 nf = ((const float4*)fb)[ld];

#define SCAN13(BV, BI)                                                         \
    {                                                                          \
        float b0_ = -3.4e38f, b1_ = -3.4e38f;                                  \
        int   i0_ = off, i1_ = off + 7;                                        \
        _Pragma("unroll")                                                      \
        for (int jj = 0; jj < 7; ++jj) {                                       \
            const float s = __int_as_float(__builtin_amdgcn_readlane(          \
                                __float_as_int(vit), off + jj)) + trrv[jj];    \
            if (s > b0_) { b0_ = s; i0_ = off + jj; }                          \
        }                                                                      \
        _Pragma("unroll")                                                      \
        for (int jj = 7; jj < 13; ++jj) {                                      \
            const float s = __int_as_float(__builtin_amdgcn_readlane(          \
                                __float_as_int(vit), off + jj)) + trrv[jj];    \
            if (s > b1_) { b1_ = s; i1_ = off + jj; }                          \
        }                                                                      \
        if (b1_ > b0_) { b0_ = b1_; i0_ = i1_; }                               \
        (BV) = b0_; (BI) = i0_;                                                \
    }
#define COMBINE(PAR, BV, BI)                                                   \
    {                                                                          \
        const float2 p0 = (PAR)[0][lane];                                      \
        const float2 p1 = (PAR)[1][lane];                                      \
        const float2 p2 = (PAR)[2][lane];                                      \
        const float2 p3 = (PAR)[3][lane];                                      \
        (BV) = p0.x; (BI) = __float_as_int(p0.y);                              \
        if (p1.x > (BV)) { (BV) = p1.x; (BI) = __float_as_int(p1.y); }         \
        if (p2.x > (BV)) { (BV) = p2.x; (BI) = __float_as_int(p2.y); }         \
        if (p3.x > (BV)) { (BV) = p3.x; (BI) = __float_as_int(p3.y); }         \
    }

    unsigned pk = 0;
    for (int c = 0; c < nchunks; ++c) {
        if (tid < 200) ((float4*)featbuf)[tid] = nf;
        {
            const int cn = (c + 1 > 63) ? 63 : c + 1;
            nf = ((const float4*)(fb + cn * 800))[ld];
        }
        asm volatile("s_waitcnt lgkmcnt(0)" ::: "memory");
        __builtin_amdgcn_s_barrier();
        asm volatile("" ::: "memory");

#pragma unroll
        for (int i = 0; i < 16; ++i) {
            const int t = (c << 4) + i;
            const float f = featbuf[i * 50 + lane];

            float bw; int iw;
            SCAN13(bw, iw)

            partial[t & 1][w][lane] = make_float2(bw, __int_as_float(iw));
            asm volatile("s_waitcnt lgkmcnt(0)" ::: "memory");
            __builtin_amdgcn_s_barrier();
            asm volatile("" ::: "memory");

            float bv; int bi;
            COMBINE(partial[t & 1], bv, bi)

            if (w == 0) {
                pk = (pk >> 8) | ((unsigned)bi << 24);
                if ((t & 3) == 3 && lane < LL)
                    *(unsigned*)(pt + t - 3) = pk;
            }
            if (t < len) {
                float nv = bv + f;
                if (t == len - 1) nv += tr_stop;
                vit = nv;
            }
        }
    }
    {
        float bw; int iw;
        SCAN13(bw, iw)
        partial[0][w][lane] = make_float2(bw, __int_as_float(iw));
        asm volatile("s_waitcnt lgkmcnt(0)" ::: "memory");
        __builtin_amdgcn_s_barrier();
        asm volatile("" ::: "memory");
        float bv; int bi;
        COMBINE(partial[0], bv, bi)
        const unsigned pat = (unsigned)bi * 0x01010101u;
        uint4 q; q.x = pat; q.y = pat; q.z = pat; q.w = pat;
        if (lane < LL)
            for (int c2 = nchunks + w; c2 < 64; c2 += 4)
                *(uint4*)(pt + (c2 << 4)) = q;
    }
    if (w == 0) {
        float m = -3.4e38f; int mi = 0;
#pragma unroll
        for (int j = 0; j < LL; ++j) {
            float s = __int_as_float(__builtin_amdgcn_readlane(__float_as_int(vit), j));
            if (s > m) { m = s; mi = j; }
        }
        if (lane == 0) { out_scores[b] = m; idx_ws[b] = mi; }
    }
#undef SCAN13
#undef COMBINE
}

extern "C" void kernel_launch(void* const* d_in, const int* in_sizes, int n_in,
                              void* d_out, int out_size, void* d_ws, size_t ws_size,
                              hipStream_t stream) {
    const float* feats = (const float*)d_in[0];
    const int*   lens  = (const int*)d_in[1];
    const float* trans = (const float*)d_in[2];

    float* scores = (float*)d_out;          // [512]
    float* paths  = scores + BB;            // [512*1024]

    int* idx_ws = (int*)d_ws;
    u8*  ptr_ws = (u8*)d_ws + PTR_OFF;

    if (ws_size >= NEED_WS) {
        float* vit_ws = (float*)((u8*)d_ws + VIT_OFF);
        viterbi_max<<<BB, 64, 0, stream>>>(feats, lens, trans, scores, idx_ws, vit_ws);
        viterbi_ptr<<<(BB * 128) / 4, 256, 0, stream>>>(lens, trans, vit_ws, ptr_ws);
    } else {
        viterbi_fwd_fb<<<BB, 256, 0, stream>>>(feats, lens, trans, scores, idx_ws, ptr_ws);
    }
    viterbi_bwd<<<BB, 64, 0, stream>>>(idx_ws, ptr_ws, paths);
}

// Round 3
// 570.156 us; speedup vs baseline: 1.3806x; 1.3806x over previous
//
#include <hip/hip_runtime.h>

typedef unsigned char u8;

#define TT 1024
#define BB 512
#define LL 50
#define STOPI 48
#define STARTI 49
#define NEGV -10000.0f

// ws layout:
//   [0, 2048)             : int idx[512]
//   [4096, 4096+B*50*T)   : u8 ptr[B][50][T]  backpointers, TRANSPOSED [label][time]
#define PTR_OFF 4096

// ---- shared building blocks ------------------------------------------------
// unpack a 50-float row (uniform LDS address, 13x ds_read_b128) and add trr
#define ROW_ADDS(ROWP, S, TRR)                                                 \
    {                                                                          \
        _Pragma("unroll")                                                      \
        for (int k_ = 0; k_ < 13; ++k_) {                                      \
            const float4 q_ = *(const float4*)((ROWP) + 4 * k_);               \
            const int j_ = 4 * k_;                                             \
            (S)[j_ + 0] = q_.x + (TRR)[j_ + 0];                                \
            (S)[j_ + 1] = q_.y + (TRR)[j_ + 1];                                \
            if (j_ + 2 < LL) (S)[j_ + 2] = q_.z + (TRR)[j_ + 2];               \
            if (j_ + 3 < LL) (S)[j_ + 3] = q_.w + (TRR)[j_ + 3];               \
        }                                                                      \
    }

// value-only max over S[0..49] via max3-friendly tree (~26 instrs)
#define MAX50(S, M)                                                            \
    {                                                                          \
        float r0_[17];                                                         \
        _Pragma("unroll")                                                      \
        for (int k_ = 0; k_ < 16; ++k_)                                        \
            r0_[k_] = fmaxf(fmaxf((S)[3*k_], (S)[3*k_+1]), (S)[3*k_+2]);       \
        r0_[16] = fmaxf((S)[48], (S)[49]);                                     \
        float r1_[6];                                                          \
        _Pragma("unroll")                                                      \
        for (int k_ = 0; k_ < 5; ++k_)                                         \
            r1_[k_] = fmaxf(fmaxf(r0_[3*k_], r0_[3*k_+1]), r0_[3*k_+2]);       \
        r1_[5] = fmaxf(r0_[15], r0_[16]);                                      \
        (M) = fmaxf(fmaxf(fmaxf(r1_[0], r1_[1]), r1_[2]),                      \
                    fmaxf(fmaxf(r1_[3], r1_[4]), r1_[5]));                     \
    }

// first-index argmax over S[0..49]: 4 parallel strict-'>' chains, block-order
// combine (exact reference tie semantics; proven pattern from r0/r1 kernels)
#define ARGMAX50(S, BI)                                                        \
    {                                                                          \
        float b0_=-3.4e38f, b1_=-3.4e38f, b2_=-3.4e38f, b3_=-3.4e38f;          \
        int   i0_=0, i1_=13, i2_=26, i3_=39;                                   \
        _Pragma("unroll")                                                      \
        for (int j_=0;  j_<13; ++j_){ const float v_=(S)[j_]; if (v_>b0_){b0_=v_;i0_=j_;} } \
        _Pragma("unroll")                                                      \
        for (int j_=13; j_<26; ++j_){ const float v_=(S)[j_]; if (v_>b1_){b1_=v_;i1_=j_;} } \
        _Pragma("unroll")                                                      \
        for (int j_=26; j_<39; ++j_){ const float v_=(S)[j_]; if (v_>b2_){b2_=v_;i2_=j_;} } \
        _Pragma("unroll")                                                      \
        for (int j_=39; j_<50; ++j_){ const float v_=(S)[j_]; if (v_>b3_){b3_=v_;i3_=j_;} } \
        if (b1_>b0_){b0_=b1_;i0_=i1_;}                                         \
        if (b2_>b0_){b0_=b2_;i0_=i2_;}                                         \
        if (b3_>b0_){b0_=b3_;i0_=i3_;}                                         \
        (BI) = i0_;                                                            \
    }

// consumer: process 4 backpointer rows [BASE, BASE+4). Rows t<=len computed
// fresh from ring[t&15]; rows t>len reuse cidx (computed once from the
// persistent ring[len&15] row, which the producer never overwrites).
#define PROCESS_GROUP(BASE)                                                    \
    {                                                                          \
        if (!have && (BASE) + 3 > len) {                                       \
            const float* rowp_ = &ring[len & 15][0];                           \
            float s_[LL];                                                      \
            ROW_ADDS(rowp_, s_, trr)                                           \
            ARGMAX50(s_, cidx)                                                 \
            have = true;                                                       \
        }                                                                      \
        unsigned pk_ = 0;                                                      \
        _Pragma("unroll 1")                                                    \
        for (int r_ = 0; r_ < 4; ++r_) {                                       \
            const int t_ = (BASE) + r_;                                        \
            int idx_;                                                          \
            if (t_ <= len) {                                                   \
                const float* rowp_ = &ring[t_ & 15][0];                        \
                float s_[LL];                                                  \
                ROW_ADDS(rowp_, s_, trr)                                       \
                ARGMAX50(s_, idx_)                                             \
            } else {                                                           \
                idx_ = cidx;                                                   \
            }                                                                  \
            pk_ |= (unsigned)idx_ << (8 * r_);                                 \
        }                                                                      \
        if (lane < LL) *(unsigned*)(pt + (BASE)) = pk_;                        \
    }

// ---------------------------------------------------------------------------
// Fused forward: 3 waves per batch.
//   wave 0: max-only serial chain, publishes vit rows to a 16-slot LDS ring.
//   waves 1,2: one iteration behind, compute argmax backpointers (4 rows each
//   per 8-step iteration) and store packed bytes.
// One bare s_barrier (+lgkmcnt(0)) per 8 steps; vmcnt never drained, so the
// producer's feats prefetch and the consumers' ptr stores stay in flight.
// ---------------------------------------------------------------------------
__global__ __launch_bounds__(192, 2) void viterbi_fused(
    const float* __restrict__ feats, const int* __restrict__ lens,
    const float* __restrict__ trans, float* __restrict__ out_scores,
    int* __restrict__ idx_ws, u8* __restrict__ ptr_ws)
{
    const int b    = blockIdx.x;
    const int tid  = threadIdx.x;
    const int lane = tid & 63;
    const int w    = __builtin_amdgcn_readfirstlane(tid >> 6);   // 0..2
    const int row  = (lane < LL) ? lane : (LL - 1);              // 'to' label

    __shared__ float ring[16][64];    // vit rows, slot = t & 15; stride 64 for
                                      // 16B-aligned float4 broadcast reads

    float trr[LL];                    // trans[row][j]  (register-resident:
#pragma unroll                        //  launch_bounds(192,2) -> VGPR<=256)
    for (int j = 0; j < LL; ++j) trr[j] = trans[row * LL + j];
    const int len = lens[b];

    if (w == 0) {
        // ---------------- producer: serial max chain ----------------
        const float tr_stop = trans[STOPI * LL + row];
        float vit = (lane == STARTI) ? 0.0f : NEGV;
        const float* fb = feats + (size_t)b * (TT * LL);

        float f[8];                   // feats prefetch ring, depth 8
#pragma unroll
        for (int i = 0; i < 8; ++i) f[i] = fb[i * LL + row];

        for (int it = 0; it < 128; ++it) {
#pragma unroll
            for (int i = 0; i < 8; ++i) {
                const int t = (it << 3) + i;
                float* rowp = &ring[t & 15][0];
                if (t <= len) {                    // publish row (pre-update)
                    if (lane < LL) rowp[lane] = vit;
                }
                if (t < len) {                     // wave-uniform
                    float s[LL];
                    ROW_ADDS(rowp, s, trr)         // read own row broadcast
                    float m; MAX50(s, m)
                    float nv = m + f[i];
                    if (t == len - 1) nv += tr_stop;
                    vit = nv;
                    int tp = t + 8; if (tp > TT - 1) tp = TT - 1;
                    f[i] = fb[(size_t)tp * LL + row];   // prefetch t+8
                }
            }
            asm volatile("s_waitcnt lgkmcnt(0)" ::: "memory");
            __builtin_amdgcn_s_barrier();
            asm volatile("" ::: "memory");
        }

        // final score / first-index argmax over vit[0..49]
        float m = -3.4e38f; int mi = 0;
#pragma unroll
        for (int j = 0; j < LL; ++j) {
            float sv = __int_as_float(__builtin_amdgcn_readlane(__float_as_int(vit), j));
            if (sv > m) { m = sv; mi = j; }
        }
        if (lane == 0) { out_scores[b] = m; idx_ws[b] = mi; }
    } else {
        // ---------------- consumers: argmax backpointers ----------------
        u8* pt = ptr_ws + (size_t)b * (TT * LL) + (size_t)row * TT;  // [to][t]
        int  cidx = 0;
        bool have = false;

        for (int it = 0; it < 128; ++it) {
            if (it > 0) {
                const int base = ((it - 1) << 3) + ((w - 1) << 2);
                PROCESS_GROUP(base)
            }
            asm volatile("s_waitcnt lgkmcnt(0)" ::: "memory");
            __builtin_amdgcn_s_barrier();
            asm volatile("" ::: "memory");
        }
        {   // tail: rows of the last iteration (producer is done; ring stable)
            const int base = (127 << 3) + ((w - 1) << 2);
            PROCESS_GROUP(base)
        }
    }
}

// ---------------------------------------------------------------------------
// Backtrack with chunked pointer-jumping; XOR-swizzled LDS (passed round 2).
// byte (s,t) lives at (s<<10) + (t ^ ((s&31)<<2)).
// ---------------------------------------------------------------------------
#define LSW(S, T) (((S) << 10) + ((T) ^ (((S) & 31) << 2)))

__global__ __launch_bounds__(64) void viterbi_bwd(
    const int* __restrict__ idx_ws, const u8* __restrict__ ptr_ws,
    float* __restrict__ out_paths)
{
    const int b = blockIdx.x;
    const int lane = threadIdx.x;

    __shared__ u8 lptr[TT * LL];    // 51200 B, swizzled [label][t]
    __shared__ u8 maps[32 * LL];
    __shared__ int entries[33];

    {   // dword-level swizzled copy
        const unsigned* src = (const unsigned*)(ptr_ws + (size_t)b * TT * LL);
        unsigned* dst = (unsigned*)lptr;
        for (int i = lane; i < (TT * LL) / 4; i += 64) {
            const int to = i >> 8;            // 256 dwords per label row
            const int t4 = i & 255;
            dst[(to << 8) + (t4 ^ (to & 31))] = src[i];
        }
    }
    __syncthreads();

    // phase 1: all 1600 (chunk, entry) walks; 25 chains per lane
    {
        int st[25], tt[25], cidx[25];
#pragma unroll
        for (int k = 0; k < 25; ++k) {
            int ww = k * 64 + lane;
            int c = ww / 50;
            int l = ww - c * 50;
            st[k] = l;
            tt[k] = c * 32 + 31;
            cidx[k] = c * 50 + l;
        }
        for (int j = 0; j < 32; ++j) {
#pragma unroll
            for (int k = 0; k < 25; ++k) {
                st[k] = lptr[LSW(st[k], tt[k])];
                tt[k] -= 1;
            }
        }
#pragma unroll
        for (int k = 0; k < 25; ++k) maps[cidx[k]] = (u8)st[k];
    }
    __syncthreads();

    const int idx = idx_ws[b];

    // phase 2: compose chunk maps sequentially
    if (lane == 0) {
        int i = idx;
        for (int c = 31; c >= 0; --c) {
            entries[c + 1] = i;
            i = maps[c * 50 + i];
        }
        entries[0] = i;
    }
    __syncthreads();

    // phase 3: re-walk all 32 chunks in parallel, writing the path
    float* po = out_paths + (size_t)b * TT;
    if (lane < 32) {
        const int c = lane;
        int s = entries[c + 1];
        for (int j = 0; j < 32; ++j) {
            int t = c * 32 + 31 - j;
            int ni = lptr[LSW(s, t)];
            if (t > 0) po[t - 1] = (float)ni;
            s = ni;
        }
    }
    if (lane == 0) po[TT - 1] = (float)idx;
}

extern "C" void kernel_launch(void* const* d_in, const int* in_sizes, int n_in,
                              void* d_out, int out_size, void* d_ws, size_t ws_size,
                              hipStream_t stream) {
    const float* feats = (const float*)d_in[0];
    const int*   lens  = (const int*)d_in[1];
    const float* trans = (const float*)d_in[2];

    float* scores = (float*)d_out;          // [512]
    float* paths  = scores + BB;            // [512*1024]

    int* idx_ws = (int*)d_ws;
    u8*  ptr_ws = (u8*)d_ws + PTR_OFF;

    viterbi_fused<<<BB, 192, 0, stream>>>(feats, lens, trans, scores, idx_ws, ptr_ws);
    viterbi_bwd<<<BB, 64, 0, stream>>>(idx_ws, ptr_ws, paths);
}

// Round 5
// 562.452 us; speedup vs baseline: 1.3995x; 1.0137x over previous
//
#include <hip/hip_runtime.h>

typedef unsigned char u8;

#define TT 1024
#define BB 512
#define LL 50
#define STOPI 48
#define STARTI 49
#define NEGV -10000.0f

// Swizzled in-LDS backpointer array lptr[50][1024] (bytes).
// dword index for (to, t4=t>>2): (to<<8) + (t4 ^ (to&31))   -> writes spread
// byte address for (s, t): same dword swizzle + (t&3)       -> reads spread
#define PDW(TO, T4) (((TO) << 8) + ((T4) ^ ((TO) & 31)))
#define PBYTE(S, T) ((((S) << 10) + (((((T) >> 2) ^ ((S) & 31))) << 2)) + ((T) & 3))

// value-only max over S[0..49] via max3 tree (~26 instrs, depth 4)
#define MAX50(S, M)                                                            \
    {                                                                          \
        float r0_[17];                                                         \
        _Pragma("unroll")                                                      \
        for (int k_ = 0; k_ < 16; ++k_)                                        \
            r0_[k_] = fmaxf(fmaxf((S)[3*k_], (S)[3*k_+1]), (S)[3*k_+2]);       \
        r0_[16] = fmaxf((S)[48], (S)[49]);                                     \
        float r1_[6];                                                          \
        _Pragma("unroll")                                                      \
        for (int k_ = 0; k_ < 5; ++k_)                                         \
            r1_[k_] = fmaxf(fmaxf(r0_[3*k_], r0_[3*k_+1]), r0_[3*k_+2]);       \
        r1_[5] = fmaxf(r0_[15], r0_[16]);                                      \
        (M) = fmaxf(fmaxf(fmaxf(r1_[0], r1_[1]), r1_[2]),                      \
                    fmaxf(fmaxf(r1_[3], r1_[4]), r1_[5]));                     \
    }

// consumer row fetch: 13 uniform-address ds_read_b128 broadcasts (LDS pipe,
// conflict-free) + 50 VALU adds. Keeps VALU issue slots for the producer.
#define ROW_ADDS(ROWP, S)                                                      \
    {                                                                          \
        _Pragma("unroll")                                                      \
        for (int k_ = 0; k_ < 13; ++k_) {                                      \
            const float4 q_ = *(const float4*)((ROWP) + 4 * k_);               \
            const int j_ = 4 * k_;                                             \
            (S)[j_ + 0] = q_.x + trr[j_ + 0];                                  \
            (S)[j_ + 1] = q_.y + trr[j_ + 1];                                  \
            if (j_ + 2 < LL) (S)[j_ + 2] = q_.z + trr[j_ + 2];                 \
            if (j_ + 3 < LL) (S)[j_ + 3] = q_.w + trr[j_ + 3];                 \
        }                                                                      \
    }

// argmax of ring row T (+trr) -- exact reference semantics: m is bitwise one
// of the a_j (fmax is pure selection, no NaNs in-range); descending eq-scan
// yields the FIRST j attaining the max == jnp.argmax tie rule.
#define ROWIDX(T, IOUT)                                                        \
    {                                                                          \
        const float* rowp_ = &ring[(T) & 15][0];                               \
        float a_[LL];                                                          \
        ROW_ADDS(rowp_, a_)                                                    \
        float m_; MAX50(a_, m_)                                                \
        int ii_ = 0;                                                           \
        _Pragma("unroll")                                                      \
        for (int j_ = LL - 1; j_ >= 0; --j_)                                   \
            if (a_[j_] == m_) ii_ = j_;                                        \
        (IOUT) = ii_;                                                          \
    }

// consumer: 4 backpointer rows [BASE, BASE+4) -> one packed dword into lptr.
// rows t<=len fresh from ring; rows t>len reuse cidx (from persistent row len:
// the producer never overwrites slot len&15 after publishing it).
#define PROCESS_GROUP(BASE)                                                    \
    {                                                                          \
        unsigned pk_ = 0;                                                      \
        _Pragma("unroll 1")                                                    \
        for (int r_ = 0; r_ < 4; ++r_) {                                       \
            const int t_ = (BASE) + r_;                                        \
            int idx_;                                                          \
            if (t_ <= len) {                                                   \
                ROWIDX(t_, idx_)                                               \
            } else {                                                           \
                if (!have) { ROWIDX(len, cidx) have = true; }                  \
                idx_ = cidx;                                                   \
            }                                                                  \
            pk_ |= (unsigned)idx_ << (8 * r_);                                 \
        }                                                                      \
        if (lane < LL)                                                         \
            ((unsigned*)lptr)[PDW(row, (BASE) >> 2)] = pk_;                    \
    }

// ---------------------------------------------------------------------------
// One kernel does everything for one batch: 3 waves.
//   wave 0 (producer, setprio 1): max-only serial chain, vit in registers,
//     broadcast via v_readlane (no LDS latency on the chain); publishes rows
//     to a 16-slot LDS ring.
//   waves 1,2 (consumers): one iteration behind, recompute argmax per row
//     (b128 LDS broadcasts) and write packed backpointers into swizzled LDS.
//   then: all 3 waves run the chunked pointer-jumping backtrack from LDS.
// trr[50] is pinned in VGPRs via asm -- the compiler rematerialized these
// loads inside the loop in every previous round (VGPR_Count 48/68).
// ---------------------------------------------------------------------------
__global__ __launch_bounds__(192, 2) void viterbi_all(
    const float* __restrict__ feats, const int* __restrict__ lens,
    const float* __restrict__ trans, float* __restrict__ out)
{
    const int b    = blockIdx.x;
    const int tid  = threadIdx.x;
    const int lane = tid & 63;
    const int w    = __builtin_amdgcn_readfirstlane(tid >> 6);   // 0..2
    const int row  = (lane < LL) ? lane : (LL - 1);              // 'to' label

    __shared__ float ring[16][64];     // vit rows, slot = t & 15
    __shared__ u8    lptr[TT * LL];    // 51200 B backpointers, swizzled
    __shared__ u8    maps[32 * LL];
    __shared__ int   entries[33];
    __shared__ int   fidx;

    float trr[LL];
#pragma unroll
    for (int j = 0; j < LL; ++j) trr[j] = trans[row * LL + j];
#pragma unroll
    for (int j = 0; j < LL; ++j) asm("" : "+v"(trr[j]));   // pin in VGPRs

    const int len  = lens[b];
    const int nit0 = (len >> 3) + 1;
    const int nit  = nit0 > 128 ? 128 : nit0;   // iterations actually needed

    if (w == 0) {
        // ---------------- producer: register-resident max chain ----------
        __builtin_amdgcn_s_setprio(1);          // critical serial chain
        const float tr_stop = trans[STOPI * LL + row];
        float vit = (lane == STARTI) ? 0.0f : NEGV;
        const float* fb = feats + (size_t)b * (TT * LL);

        float f[8];                     // feats prefetch ring, depth 8
#pragma unroll
        for (int i = 0; i < 8; ++i) f[i] = fb[i * LL + row];

        for (int it = 0; it < nit; ++it) {
#pragma unroll
            for (int i = 0; i < 8; ++i) {
                const int t = (it << 3) + i;
                if (t <= len) {                     // publish pre-update row
                    if (lane < LL) ring[t & 15][lane] = vit;
                }
                if (t < len) {                      // wave-uniform
                    float a[LL];
#pragma unroll
                    for (int j = 0; j < LL; ++j)
                        a[j] = __int_as_float(__builtin_amdgcn_readlane(
                                   __float_as_int(vit), j)) + trr[j];
                    float m; MAX50(a, m)
                    float nv = m + f[i];
                    if (t == len - 1) nv += tr_stop;
                    vit = nv;
                    int tp = t + 8; if (tp > TT - 1) tp = TT - 1;
                    f[i] = fb[(size_t)tp * LL + row];   // prefetch t+8
                }
            }
            asm volatile("s_waitcnt lgkmcnt(0)" ::: "memory");
            __builtin_amdgcn_s_barrier();
            asm volatile("" ::: "memory");
        }
        __builtin_amdgcn_s_setprio(0);

        // final score / first-index argmax
        float m = -3.4e38f; int mi = 0;
#pragma unroll
        for (int j = 0; j < LL; ++j) {
            float sv = __int_as_float(__builtin_amdgcn_readlane(__float_as_int(vit), j));
            if (sv > m) { m = sv; mi = j; }
        }
        if (lane == 0) { out[b] = m; fidx = mi; }
    } else {
        // ---------------- consumers: argmax backpointers -> LDS ----------
        int  cidx = 0;
        bool have = false;

        for (int it = 0; it < nit; ++it) {
            if (it > 0) {
                const int base = ((it - 1) << 3) + ((w - 1) << 2);
                PROCESS_GROUP(base)
            }
            asm volatile("s_waitcnt lgkmcnt(0)" ::: "memory");
            __builtin_amdgcn_s_barrier();
            asm volatile("" ::: "memory");
        }

        // tail: rows of the last iteration (ring is stable now)
        const int base0 = (nit - 1) << 3;
        PROCESS_GROUP(base0 + ((w - 1) << 2))

        // frozen pattern fill for t >= base0+8 (all > len by construction)
        const int t0f = base0 + 8;
        if (t0f < TT) {
            if (!have) { ROWIDX(len, cidx) have = true; }
            if (lane < LL) {
                const unsigned pat = (unsigned)cidx * 0x01010101u;
                int tq = t0f;
                if (tq & 8) {                       // 8-byte prefix
                    if (w == 1) {
                        ((unsigned*)lptr)[PDW(row, tq >> 2)]     = pat;
                        ((unsigned*)lptr)[PDW(row, (tq >> 2)+1)] = pat;
                    }
                    tq += 8;
                }
                for (int t4 = (tq >> 2) + (w - 1) * 4; t4 < 256; t4 += 8) {
                    ((unsigned*)lptr)[PDW(row, t4 + 0)] = pat;
                    ((unsigned*)lptr)[PDW(row, t4 + 1)] = pat;
                    ((unsigned*)lptr)[PDW(row, t4 + 2)] = pat;
                    ((unsigned*)lptr)[PDW(row, t4 + 3)] = pat;
                }
            }
        }
    }

    __syncthreads();   // all backpointers in LDS; fidx visible

    // ---------------- backtrack (same block, from LDS) --------------------
    // phase 1: all 1600 (chunk, entry) walks; 9 chains per thread
    {
        int st[9], ttt[9], ci[9];
#pragma unroll
        for (int k = 0; k < 9; ++k) {
            int id = tid + 192 * k;
            int valid = id < 1600;
            int idc = valid ? id : 1599;
            int c = idc / 50;
            int l = idc - c * 50;
            st[k] = l; ttt[k] = c * 32 + 31; ci[k] = valid ? idc : -1;
        }
        for (int j = 0; j < 32; ++j) {
#pragma unroll
            for (int k = 0; k < 9; ++k) {
                st[k] = lptr[PBYTE(st[k], ttt[k])];
                ttt[k] -= 1;
            }
        }
#pragma unroll
        for (int k = 0; k < 9; ++k)
            if (ci[k] >= 0) maps[ci[k]] = (u8)st[k];
    }
    __syncthreads();

    const int idx = fidx;

    // phase 2: compose chunk maps sequentially
    if (tid == 0) {
        int i = idx;
        for (int c = 31; c >= 0; --c) {
            entries[c + 1] = i;
            i = maps[c * 50 + i];
        }
        entries[0] = i;
    }
    __syncthreads();

    // phase 3: re-walk 32 chunks in parallel, writing the path
    float* po = out + BB + (size_t)b * TT;
    if (tid < 32) {
        const int c = tid;
        int s = entries[c + 1];
        for (int j = 0; j < 32; ++j) {
            int t = c * 32 + 31 - j;
            int ni = lptr[PBYTE(s, t)];
            if (t > 0) po[t - 1] = (float)ni;   // paths[t-1] = back_seq[t]
            s = ni;
        }
    }
    if (tid == 0) po[TT - 1] = (float)idx;      // paths[T-1] = argmax(vit)
}

extern "C" void kernel_launch(void* const* d_in, const int* in_sizes, int n_in,
                              void* d_out, int out_size, void* d_ws, size_t ws_size,
                              hipStream_t stream) {
    const float* feats = (const float*)d_in[0];
    const int*   lens  = (const int*)d_in[1];
    const float* trans = (const float*)d_in[2];

    viterbi_all<<<BB, 192, 0, stream>>>(feats, lens, trans, (float*)d_out);
}